// Round 12
// baseline (283.200 us; speedup 1.0000x reference)
//
#include <hip/hip_runtime.h>
#include <math.h>

// GatedPrototypeDistillationLoss, MI355X gfx950 — round 12.
// Round-11 finding: capacity is 3 blocks/CU but grid=512 pins 2/CU.
//  * kmain_v10 = v9 transposed (P.E^T) BK16 structure + SPLIT-K x2:
//    grid 1024 (512 row-tiles x 2 kh-halves), 128 steps/block, 3 blocks/CU.
//    Blocks write per-row partial (m1,m2,s,u,idx); kmerge combines.
//  * E stays fp32: B-side (64 rows x 16 dims/step) is reg-staged with
//    on-the-fly hi/lo split (T14: load at S(t-1), convert+ds_write at S(t)).
//    Kills the 64MB Ehi/Elo ws buffers and the 21us kprep_e2 pass.
//  * counted protocol per wave per step: [1 B-load(reg), 4 A-gload_lds];
//    barrier-2 vmcnt(5); B-reg use guarded by compiler dependency wait.
//  * kprep_p / krescore4 / kreduce2 unchanged. Revert target: round 8.

#define NB 32768
#define ND 512
#define NK 2048
#define TEMPR 0.07f
#define INV_T 14.285714285714286f
#define DX 1.4285714e-4f  // near-tie margin in x-domain (=1e-5 sim / T)

typedef unsigned short u16;
typedef unsigned long long u64;
using bf16x8 = __attribute__((ext_vector_type(8))) short;
using u16x8 = __attribute__((ext_vector_type(8))) unsigned short;
using f32x16 = __attribute__((ext_vector_type(16))) float;

__device__ inline u16 bf_hi(float x) {  // fp32 -> bf16 bits, RNE
  unsigned u = __float_as_uint(x);
  u = u + 0x7FFFu + ((u >> 16) & 1u);
  return (u16)(u >> 16);
}
__device__ inline float bf_tof(u16 h) {
  return __uint_as_float(((unsigned)h) << 16);
}
__device__ inline void gload_lds16(const void* g, void* l) {
  __builtin_amdgcn_global_load_lds((const __attribute__((address_space(1))) void*)g,
                                   (__attribute__((address_space(3))) void*)l, 16, 0, 0);
}
#define MF(a, b, c) __builtin_amdgcn_mfma_f32_32x32x16_bf16((a), (b), (c), 0, 0, 0)

#define WAIT_LGKM0 { asm volatile("s_waitcnt lgkmcnt(0)" ::: "memory"); \
                     __builtin_amdgcn_sched_barrier(0); }
#define WAIT_VM5   { asm volatile("s_waitcnt vmcnt(5)" ::: "memory"); \
                     __builtin_amdgcn_sched_barrier(0); }
#define SBAR       { __builtin_amdgcn_s_barrier(); \
                     __builtin_amdgcn_sched_barrier(0); }

// ---- kernel 1: P -> normalized bf16 hi/lo (BK=16 tiles) + inv_p ------------
// Phi/Plo u16 layout: [kt(8)][dt(32)][g(2)][proto(256)][8]
__global__ __launch_bounds__(256) void kprep_p(const float* __restrict__ P,
                                               u16* __restrict__ Phi,
                                               u16* __restrict__ Plo,
                                               float* __restrict__ invp,
                                               int* __restrict__ cnt) {
  if (blockIdx.x == 0 && threadIdx.x == 0) *cnt = 0;
  const int lane = threadIdx.x & 63, w = threadIdx.x >> 6;
  const int p = blockIdx.x * 4 + w;  // grid 512 -> 2048 rows
  const float4* pr = (const float4*)(P + (size_t)p * ND);
  float4 a = pr[2 * lane], b = pr[2 * lane + 1];  // granule `lane`: d=8*lane..+7
  float ss = a.x * a.x + a.y * a.y + a.z * a.z + a.w * a.w
           + b.x * b.x + b.y * b.y + b.z * b.z + b.w * b.w;
#pragma unroll
  for (int off = 32; off > 0; off >>= 1) ss += __shfl_xor(ss, off);
  const float inv = 1.0f / fmaxf(sqrtf(ss), 1e-12f);
  if (lane == 0) invp[p] = inv;
  u16x8 h8, l8;
#define PCNV(j, f) { float n_ = (f) * inv; u16 hb_ = bf_hi(n_); \
  h8[j] = hb_; l8[j] = bf_hi(n_ - bf_tof(hb_)); }
  PCNV(0, a.x) PCNV(1, a.y) PCNV(2, a.z) PCNV(3, a.w)
  PCNV(4, b.x) PCNV(5, b.y) PCNV(6, b.z) PCNV(7, b.w)
#undef PCNV
  const int kt = p >> 8, pl = p & 255;
  // granule lane = dt*2 + g with dt in [0,32), g in {0,1}
  const size_t idx =
      ((size_t)((kt * 32 + (lane >> 1)) * 2 + (lane & 1)) * 256 + pl) * 8;
  *(u16x8*)(Phi + idx) = h8;
  *(u16x8*)(Plo + idx) = l8;
}

// ---------------- kernel 2: E inverse norms only (E stays fp32) -------------
__global__ __launch_bounds__(256) void kprep_e(const float* __restrict__ E,
                                               float* __restrict__ inv_e) {
  const int lane = threadIdx.x & 63, w = threadIdx.x >> 6;
  const int row = blockIdx.x * 4 + w;  // grid 8192 -> 32768 rows
  const float4* er = (const float4*)(E + (size_t)row * ND);
  float4 a = er[lane], b = er[lane + 64];
  float ss = a.x * a.x + a.y * a.y + a.z * a.z + a.w * a.w
           + b.x * b.x + b.y * b.y + b.z * b.z + b.w * b.w;
#pragma unroll
  for (int off = 32; off > 0; off >>= 1) ss += __shfl_xor(ss, off);
  if (lane == 0) inv_e[row] = 1.0f / fmaxf(sqrtf(ss), 1e-12f);
}

// online update with exact top-2 tracking (x-domain logit, fixed offset),
// substate i (per acc tile)
#define UPD2S(i, vv, pp) { \
  float x_ = fmaf((vv), INV_T, -INV_T); \
  float e_ = __expf(x_); \
  sS[i] += e_; uS[i] = fmaf(x_, e_, uS[i]); \
  bool u1_ = x_ > mm1[i]; \
  float lo_ = u1_ ? mm1[i] : x_; \
  mm2[i] = fmaxf(mm2[i], lo_); \
  mm1[i] = u1_ ? x_ : mm1[i]; \
  ixx[i] = u1_ ? (pp) : ixx[i]; }

// ====== kernel 3: transposed MFMA GEMM, split-K x2, fp32-E reg-staging ======
__global__ __launch_bounds__(256, 3) void kmain_v10(
    const float* __restrict__ E, const float* __restrict__ inv_e,
    const u16* __restrict__ PhiG, const u16* __restrict__ PloG,
    float4* __restrict__ partA, float* __restrict__ partB) {
  // LDS u16 layouts: A(protos) [g(2)][proto(256)][8] ; B(E-rows) [g(2)][erow(64)][8]
  __shared__ u16 Ahi[2][4096], Alo[2][4096];   // 32 KB
  __shared__ u16 Bhi[2][1024], Blo[2][1024];   // 8 KB

  const int t = threadIdx.x;
  const int lane = t & 63;
  const int w = t >> 6;
  const int wr = w & 1;   // proto half (protos wr*128..+127 of the kt tile)
  const int wc = w >> 1;  // E-row half (erows wc*32..+31)
  const int c = lane & 31, h = lane >> 5;
  const int swz = (blockIdx.x & 7) * 128 + (blockIdx.x >> 3);  // 1024 = 8*128
  const int rt = swz >> 1, kh = swz & 1;  // row-tile, K-half
  const int row0 = rt * 64;

  // A staging (protos): 2 hi + 2 lo instrs per wave; slot doubles as src offset
  int aoff[2];
#pragma unroll
  for (int i = 0; i < 2; ++i) aoff[i] = ((w * 2 + i) * 64 + lane) * 8;
  const int abase = kh * 128 * 4096;  // kh's 128 tiles of 4096 u16

  // B staging (E-rows, fp32 source): wave w handles dims-quad h2=w of 16.
  // thread -> (row=lane, 4 dims at (dt*16 + w*4)); write ushort4 (8B) hi+lo.
  const float* Brow = E + (size_t)(row0 + lane) * ND + w * 4;
  const float inve = inv_e[row0 + lane];
  const int bws = ((w >> 1) * 64 + lane) * 8 + (w & 1) * 4;

  // fragment-read offsets (u16 units), lane-contiguous 16B -> conflict-free
  const int arb = (h * 256 + wr * 128 + c) * 8;  // + i*256 for proto tile i
  const int bro = (h * 64 + wc * 32 + c) * 8;

  f32x16 acc0, acc1, acc2, acc3;
#pragma unroll
  for (int i = 0; i < 16; ++i) { acc0[i] = 0.f; acc1[i] = 0.f; acc2[i] = 0.f; acc3[i] = 0.f; }
  // 4 substates (one per proto tile): 20 regs of softmax state
  float sS[4], uS[4], mm1[4], mm2[4];
  int ixx[4];
#pragma unroll
  for (int i = 0; i < 4; ++i) {
    sS[i] = 0.f; uS[i] = 0.f; mm1[i] = -3.0e38f; mm2[i] = -3.0e38f; ixx[i] = 0;
  }

#define SA10(tile_u16, nx) { \
  _Pragma("unroll") \
  for (int i = 0; i < 2; ++i) { \
    gload_lds16(PhiG + abase + (tile_u16) + aoff[i], &Ahi[nx][aoff[i]]); \
    gload_lds16(PloG + abase + (tile_u16) + aoff[i], &Alo[nx][aoff[i]]); \
  } }
#define BCNV(v) { ushort4 h4, l4; float n_; u16 hb_; \
  n_ = (v).x * inve; hb_ = bf_hi(n_); h4.x = hb_; l4.x = bf_hi(n_ - bf_tof(hb_)); \
  n_ = (v).y * inve; hb_ = bf_hi(n_); h4.y = hb_; l4.y = bf_hi(n_ - bf_tof(hb_)); \
  n_ = (v).z * inve; hb_ = bf_hi(n_); h4.z = hb_; l4.z = bf_hi(n_ - bf_tof(hb_)); \
  n_ = (v).w * inve; hb_ = bf_hi(n_); h4.w = hb_; l4.w = bf_hi(n_ - bf_tof(hb_)); \
  *(ushort4*)&Bhi[cur][bws] = h4; *(ushort4*)&Blo[cur][bws] = l4; }

  // ---- prologue: B(0)->buf0, B(1)->buf1 synchronously; A(0),A(1) issued;
  //      B-regs for step 2 in flight. End invariant: outstanding [B2, A1x4].
  {
    const int cur = 0;
    float4 v = *(const float4*)(Brow + 0 * 16);
    BCNV(v)
  }
  {
    const int cur = 1;
    float4 v = *(const float4*)(Brow + 1 * 16);
    BCNV(v)
  }
  SA10(0 * 4096, 0);
  float4 bstg = *(const float4*)(Brow + 2 * 16);  // step-2 dims, written at S(0)
  SA10(1 * 4096, 1);
  WAIT_VM5;  // A(0) done (retires the 4 oldest; leaves [bstg, A1x4])
  WAIT_LGKM0;
  SBAR;

#pragma unroll 2
  for (int step = 0; step < 128; ++step) {
    const int cur = step & 1;
    // ---- phase R: all 10 fragment reads from buf[cur] ----
    const bf16x8 bh = *(const bf16x8*)&Bhi[cur][bro];
    const bf16x8 bl = *(const bf16x8*)&Blo[cur][bro];
    const bf16x8 ah0 = *(const bf16x8*)&Ahi[cur][arb];
    const bf16x8 ah1 = *(const bf16x8*)&Ahi[cur][arb + 256];
    const bf16x8 ah2 = *(const bf16x8*)&Ahi[cur][arb + 512];
    const bf16x8 ah3 = *(const bf16x8*)&Ahi[cur][arb + 768];
    const bf16x8 al0 = *(const bf16x8*)&Alo[cur][arb];
    const bf16x8 al1 = *(const bf16x8*)&Alo[cur][arb + 256];
    const bf16x8 al2 = *(const bf16x8*)&Alo[cur][arb + 512];
    const bf16x8 al3 = *(const bf16x8*)&Alo[cur][arb + 768];

    // ---- MFMA pass 1 (Ahi x Bhi) ----
    acc0 = MF(ah0, bh, acc0); acc1 = MF(ah1, bh, acc1);
    acc2 = MF(ah2, bh, acc2); acc3 = MF(ah3, bh, acc3);

    // ---- barrier 1: all waves done READING buf[cur]; no vmcnt drain ----
    WAIT_LGKM0;
    SBAR;

    // ---- phase S: write B(step+2) from regs (compiler inserts the exact
    //      vmcnt for bstg), reload bstg for step+3, stage A(step+2) ----
    BCNV(bstg)  // into buf[cur] = buf[(step+2)&1]
    const int nb = (step < 125) ? step + 3 : 127;
    bstg = *(const float4*)(Brow + (size_t)(nb & 31) * 16);
    const int ns = (step < 126) ? step + 2 : 127;  // tail dup, never read
    SA10(ns * 4096, cur);

    // ---- MFMA passes 2,3 (Ahi x Blo, Alo x Bhi) ----
    acc0 = MF(ah0, bl, acc0); acc1 = MF(ah1, bl, acc1);
    acc2 = MF(ah2, bl, acc2); acc3 = MF(ah3, bl, acc3);
    acc0 = MF(al0, bh, acc0); acc1 = MF(al1, bh, acc1);
    acc2 = MF(al2, bh, acc2); acc3 = MF(al3, bh, acc3);

    if ((step & 31) == 31) {  // kt-tile digest (overlaps in-flight stages)
      const int pb = (kh * 4 + (step >> 5)) * 256 + wr * 128 + 4 * h;
#define DIG(i, ACC) { \
  _Pragma("unroll") \
  for (int r = 0; r < 16; ++r) { \
    UPD2S(i, ACC[r], pb + (i)*32 + (r & 3) + 8 * (r >> 2)) \
    ACC[r] = 0.f; \
  } }
      DIG(0, acc0)
      DIG(1, acc1)
      DIG(2, acc2)
      DIG(3, acc3)
#undef DIG
    }

    // ---- barrier 2: retire ONLY step t+1's 4 A-gloads (counted vmcnt) ----
    WAIT_VM5;  // leaves [bstg, A(t+2)x4]
    SBAR;
  }

  __syncthreads();  // full drain (tail dup-stages still write Ahi/Bhi)

  // ---- merge 4 substates in-lane (ascending proto tiles; idx tie-break) ----
  float s = 0.f, u = 0.f, m = -3.0e38f, m2f = -3.0e38f;
  int idx = 0;
#pragma unroll
  for (int i = 0; i < 4; ++i) {
    s += sS[i]; u += uS[i];
    bool up = (mm1[i] > m) || (mm1[i] == m && ixx[i] < idx);
    m2f = fmaxf(m2f, mm2[i]);
    m2f = fmaxf(m2f, up ? m : mm1[i]);
    m = up ? mm1[i] : m;
    idx = up ? ixx[i] : idx;
  }

  // ---- h-merge: lanes c and c+32 hold complementary proto halves ----
  {
    float mo = __shfl_xor(m, 32);
    float so = __shfl_xor(s, 32);
    float uo = __shfl_xor(u, 32);
    float m2o = __shfl_xor(m2f, 32);
    int io = __shfl_xor(idx, 32);
    s += so; u += uo;
    bool up = (mo > m) || (mo == m && io < idx);
    m2f = fmaxf(m2f, m2o);
    m2f = fmaxf(m2f, up ? m : mo);
    m = up ? mo : m;
    idx = up ? io : idx;
  }

  // ---- cross-wave (wr) merge via LDS (alias onto Ahi, compute done) ----
  float* mg = (float*)&Ahi[0][0];  // [wc(2)][wr(2)][32 erows][6]
  if (lane < 32) {
    const int base = ((wc * 2 + wr) * 32 + c) * 6;
    mg[base + 0] = m;
    mg[base + 1] = s;
    mg[base + 2] = u;
    mg[base + 3] = __int_as_float(idx);
    mg[base + 4] = m2f;
  }
  __syncthreads();

  if (wr == 0 && lane < 32) {  // waves 0 and 2; erow = wc*32 + lane
    const int b0 = ((wc * 2 + 0) * 32 + lane) * 6;
    const int b1 = ((wc * 2 + 1) * 32 + lane) * 6;
    float m1a = mg[b0], s0 = mg[b0 + 1], u0 = mg[b0 + 2];
    int i0 = __float_as_int(mg[b0 + 3]);
    float m2a = mg[b0 + 4];
    float m1b = mg[b1], s1 = mg[b1 + 1], u1 = mg[b1 + 2];
    int i1 = __float_as_int(mg[b1 + 3]);
    float m2b = mg[b1 + 4];

    bool up = (m1b > m1a) || (m1b == m1a && i1 < i0);
    float mf = fmaxf(m1a, m1b);
    float m2ff = fmaxf(fmaxf(m2a, m2b), fminf(m1a, m1b));
    int idxf = up ? i1 : i0;
    float sf = s0 + s1, uf = u0 + u1;

    const int grow = row0 + wc * 32 + lane;
    partA[(grow << 1) | kh] = make_float4(mf, sf, uf, __int_as_float(idxf));
    partB[(grow << 1) | kh] = m2ff;
  }
}

// ------- kernel 3.5: merge the two K-half partials per row ------------------
__global__ __launch_bounds__(256) void kmerge(
    const float4* __restrict__ partA, const float* __restrict__ partB,
    const float* __restrict__ BS, const float* __restrict__ CONF,
    float* __restrict__ tau_ws, float* __restrict__ gd,
    float* __restrict__ gate_out, int* __restrict__ cnt,
    int* __restrict__ flags, u64* __restrict__ pk) {
  const int row = blockIdx.x * 256 + threadIdx.x;  // grid 128 -> 32768 rows
  float4 a = partA[row * 2], b = partA[row * 2 + 1];
  float m2a = partB[row * 2], m2b = partB[row * 2 + 1];
  float m1a = a.x, s0 = a.y, u0 = a.z;
  int i0 = __float_as_int(a.w);
  float m1b = b.x, s1 = b.y, u1 = b.z;
  int i1 = __float_as_int(b.w);

  // kh0 protos all < kh1 protos: strict > keeps first-max on ties
  bool up = m1b > m1a;
  float m = fmaxf(m1a, m1b);
  float m2f = fmaxf(fmaxf(m2a, m2b), fminf(m1a, m1b));
  int idx = up ? i1 : i0;
  bool flg = (m - m2f) < DX;  // exact: final top-2 gap below margin
  float s = s0 + s1, u = u0 + u1;

  float ent = logf(s) - u / s;  // = lse - E[logit]
  float tau = 0.5f - 0.2f * (ent * (1.0f / (7.6246190071f + 1e-8f)));
  float simmax = fmaf(m, TEMPR, 1.0f);  // m is (sim-1)/T
  float dist = sqrtf(fmaxf(2.0f - 2.0f * simmax, 0.0f));
  float g = CONF[idx] / (1.0f + __expf(-(BS[row] - tau) * INV_T));
  gate_out[row] = g;
  gd[row] = g * dist;
  tau_ws[row] = tau;
  if (flg) {
    pk[row] = 0ull;  // init merge slot for krescore4
    int p = atomicAdd(cnt, 1);
    flags[p] = row;
  }
}

// --- kernel 4: fp32 rescore, chunked (16 chunks/row fan out over blocks) ----
__global__ __launch_bounds__(256) void krescore4(
    const float* __restrict__ E, const float* __restrict__ P,
    const float* __restrict__ invp, const int* __restrict__ cnt,
    const int* __restrict__ flags, u64* __restrict__ pk) {
  const int n = *cnt;
  const int total = n * 16;
  const int t = threadIdx.x;
  const int k = t & 15;   // lane in 16-lane group
  const int G = t >> 4;   // group 0..15

  for (int ch = blockIdx.x; ch < total; ch += gridDim.x) {
    const int j = ch >> 4, q = ch & 15;
    const int row = flags[j];
    float4 e[8];
    float ss = 0.f;
    const float4* er = (const float4*)(E + (size_t)row * ND);
#pragma unroll
    for (int i = 0; i < 8; ++i) {
      e[i] = er[k + 16 * i];
      ss += e[i].x * e[i].x + e[i].y * e[i].y + e[i].z * e[i].z + e[i].w * e[i].w;
    }
#pragma unroll
    for (int o = 1; o < 16; o <<= 1) ss += __shfl_xor(ss, o);
    const float inv = 1.0f / fmaxf(sqrtf(ss), 1e-12f);
#pragma unroll
    for (int i = 0; i < 8; ++i) {
      e[i].x *= inv; e[i].y *= inv; e[i].z *= inv; e[i].w *= inv;
    }

    float best = -3.0e38f;
    int bidx = NK;
#pragma unroll 2
    for (int m = 0; m < 8; ++m) {  // ascending p within group: first-max kept
      const int p = q * 128 + G + 16 * m;
      const float4* pr = (const float4*)(P + (size_t)p * ND);
      float dot = 0.f;
#pragma unroll
      for (int i = 0; i < 8; ++i) {
        float4 a = pr[k + 16 * i];
        dot = fmaf(a.x, e[i].x, dot); dot = fmaf(a.y, e[i].y, dot);
        dot = fmaf(a.z, e[i].z, dot); dot = fmaf(a.w, e[i].w, dot);
      }
#pragma unroll
      for (int o = 1; o < 16; o <<= 1) dot += __shfl_xor(dot, o);
      float sim = dot * invp[p];
      if (sim > best) { best = sim; bidx = p; }
    }
    if (k == 0) {
      unsigned u = __float_as_uint(best);
      unsigned ord = (u & 0x80000000u) ? ~u : (u | 0x80000000u);
      u64 v = ((u64)ord << 32) | (unsigned)(NK - bidx);
      atomicMax(pk + row, v);
    }
  }
}

// ------- kernel 5: flagged-row fixup (unpack pk) + deterministic mean -------
__global__ __launch_bounds__(1024) void kreduce2(
    float* __restrict__ gd, const float* __restrict__ BS,
    const float* __restrict__ CONF, const float* __restrict__ tau_ws,
    const int* __restrict__ cnt, const int* __restrict__ flags,
    const u64* __restrict__ pk, float* __restrict__ out0,
    float* __restrict__ gate_out) {
  __shared__ float red[1024];
  const int t = threadIdx.x;

  const int n = *cnt;
  for (int j = t; j < n; j += 1024) {
    const int row = flags[j];
    const u64 v = pk[row];
    const unsigned hi = (unsigned)(v >> 32);
    const int idx = NK - (int)(v & 0xFFFFFFFFu);
    const float sim = (hi & 0x80000000u) ? __uint_as_float(hi & 0x7FFFFFFFu)
                                         : __uint_as_float(~hi);
    const float tau = tau_ws[row];
    const float dist = sqrtf(fmaxf(2.0f - 2.0f * sim, 0.0f));
    const float g = CONF[idx] / (1.0f + __expf(-(BS[row] - tau) * INV_T));
    gate_out[row] = g;
    gd[row] = g * dist;
  }
  __syncthreads();  // block-wide visibility of gd fixups

  float s = 0.f;
  const float4* g4 = (const float4*)gd;
  for (int i = t; i < 8192; i += 1024) {
    float4 v = g4[i];
    s += (v.x + v.y) + (v.z + v.w);
  }
  red[t] = s;
  __syncthreads();
  for (int off = 512; off > 0; off >>= 1) {
    if (t < off) red[t] += red[t + off];
    __syncthreads();
  }
  if (t == 0) out0[0] = red[0] * (1.0f / 32768.0f);
}

extern "C" void kernel_launch(void* const* d_in, const int* in_sizes, int n_in,
                              void* d_out, int out_size, void* d_ws, size_t ws_size,
                              hipStream_t stream) {
  const float* E = (const float*)d_in[0];
  const float* BS = (const float*)d_in[1];
  const float* P = (const float*)d_in[2];
  const float* CONF = (const float*)d_in[3];
  float* out = (float*)d_out;  // [0]=L_proto, [1..32768]=gate

  char* wsb = (char*)d_ws;
  u16* Phi = (u16*)wsb;                                   // 2 MB @ 0 (BK16 tiles)
  u16* Plo = (u16*)(wsb + ((size_t)2 << 20));             // 2 MB @ 2M
  char* tail = wsb + ((size_t)4 << 20);
  float* inv_e = (float*)tail;                            // 128 KB
  float* tau_ws = (float*)(tail + 131072);                // 128 KB
  float* gd = (float*)(tail + 2 * 131072);                // 128 KB
  int* flags = (int*)(tail + 3 * 131072);                 // 128 KB
  int* cnt = (int*)(tail + 4 * 131072);                   // 4 KB
  float* invp = (float*)(tail + 4 * 131072 + 4096);       // 8 KB
  u64* pk = (u64*)(tail + 4 * 131072 + 12288);            // 256 KB
  float4* partA = (float4*)(tail + ((size_t)1 << 20));    // 1 MB @ tail+1M
  float* partB = (float*)(tail + ((size_t)2 << 20));      // 256 KB @ tail+2M

  kprep_p<<<512, 256, 0, stream>>>(P, Phi, Plo, invp, cnt);
  kprep_e<<<8192, 256, 0, stream>>>(E, inv_e);
  kmain_v10<<<1024, 256, 0, stream>>>(E, inv_e, Phi, Plo, partA, partB);
  kmerge<<<128, 256, 0, stream>>>(partA, partB, BS, CONF, tau_ws, gd, out + 1,
                                  cnt, flags, pk);
  krescore4<<<2048, 256, 0, stream>>>(E, P, invp, cnt, flags, pk);
  kreduce2<<<1, 1024, 0, stream>>>(gd, BS, CONF, tau_ws, cnt, flags, pk,
                                   out, out + 1);
}

// Round 13
// 262.090 us; speedup vs baseline: 1.0805x; 1.0805x over previous
//
#include <hip/hip_runtime.h>
#include <math.h>

// GatedPrototypeDistillationLoss, MI355X gfx950 — round 13 (= round 8 banked).
// Rounds 9-12 post-mortem: every occupancy raise (8-wave blocks, BK16 3/CU,
// transposed+split-K) either spilled (unified VGPR file: state+acc+frags needs
// >128 arch regs) or failed to engage (residency stuck at 2 blocks/CU).
// Revert to the verified best: round-8 kmain_v6 (216us, MfmaUtil 43.5%,
// conflicts 2048, no spill) + one safe micro-opt: kprep_p and kprep_e2 fused
// into a single launch (block-uniform branch).

#define NB 32768
#define ND 512
#define NK 2048
#define TEMPR 0.07f
#define INV_T 14.285714285714286f
#define DX 1.4285714e-4f  // near-tie margin in x-domain (=1e-5 sim / T)

typedef unsigned short u16;
typedef unsigned long long u64;
using bf16x8 = __attribute__((ext_vector_type(8))) short;
using u16x8 = __attribute__((ext_vector_type(8))) unsigned short;
using f32x16 = __attribute__((ext_vector_type(16))) float;

__device__ inline u16 bf_hi(float x) {  // fp32 -> bf16 bits, RNE
  unsigned u = __float_as_uint(x);
  u = u + 0x7FFFu + ((u >> 16) & 1u);
  return (u16)(u >> 16);
}
__device__ inline float bf_tof(u16 h) {
  return __uint_as_float(((unsigned)h) << 16);
}
__device__ inline void gload_lds16(const void* g, void* l) {
  __builtin_amdgcn_global_load_lds((const __attribute__((address_space(1))) void*)g,
                                   (__attribute__((address_space(3))) void*)l, 16, 0, 0);
}
#define MF(a, b, c) __builtin_amdgcn_mfma_f32_32x32x16_bf16((a), (b), (c), 0, 0, 0)

#define WAIT_LGKM0 { asm volatile("s_waitcnt lgkmcnt(0)" ::: "memory"); \
                     __builtin_amdgcn_sched_barrier(0); }
#define WAIT_VM10  { asm volatile("s_waitcnt vmcnt(10)" ::: "memory"); \
                     __builtin_amdgcn_sched_barrier(0); }
#define SBAR       { __builtin_amdgcn_s_barrier(); \
                     __builtin_amdgcn_sched_barrier(0); }

// ---- kernel 1 (fused prep): blocks 0..511 -> P; blocks 512..8703 -> E ------
// Phi/Plo u16 layout: [kt(8)][dt(16)][g(4)][proto(256)][8]
__global__ __launch_bounds__(256) void kprep_all(
    const float* __restrict__ P, const float* __restrict__ E,
    u16* __restrict__ Phi, u16* __restrict__ Plo, float* __restrict__ invp,
    u16* __restrict__ Ehi, u16* __restrict__ Elo, int* __restrict__ cnt) {
  const int lane = threadIdx.x & 63, w = threadIdx.x >> 6;
  if (blockIdx.x < 512) {
    if (blockIdx.x == 0 && threadIdx.x == 0) *cnt = 0;
    const int p = blockIdx.x * 4 + w;  // 2048 proto rows
    const float4* pr = (const float4*)(P + (size_t)p * ND);
    float4 a = pr[2 * lane], b = pr[2 * lane + 1];  // granule `lane`
    float ss = a.x * a.x + a.y * a.y + a.z * a.z + a.w * a.w
             + b.x * b.x + b.y * b.y + b.z * b.z + b.w * b.w;
#pragma unroll
    for (int off = 32; off > 0; off >>= 1) ss += __shfl_xor(ss, off);
    const float inv = 1.0f / fmaxf(sqrtf(ss), 1e-12f);
    if (lane == 0) invp[p] = inv;
    u16x8 h8, l8;
#define PCNV8(j, f) { float n_ = (f) * inv; u16 hb_ = bf_hi(n_); \
  h8[j] = hb_; l8[j] = bf_hi(n_ - bf_tof(hb_)); }
    PCNV8(0, a.x) PCNV8(1, a.y) PCNV8(2, a.z) PCNV8(3, a.w)
    PCNV8(4, b.x) PCNV8(5, b.y) PCNV8(6, b.z) PCNV8(7, b.w)
#undef PCNV8
    const int kt = p >> 8, pl = p & 255;
    const size_t idx =
        ((size_t)((kt * 16 + (lane >> 2)) * 4 + (lane & 3)) * 256 + pl) * 8;
    *(u16x8*)(Phi + idx) = h8;
    *(u16x8*)(Plo + idx) = l8;
  } else {
    const int row = (blockIdx.x - 512) * 4 + w;  // 32768 E rows
    const float4* er = (const float4*)(E + (size_t)row * ND);
    float4 a = er[lane], b = er[lane + 64];
    float ss = a.x * a.x + a.y * a.y + a.z * a.z + a.w * a.w
             + b.x * b.x + b.y * b.y + b.z * b.z + b.w * b.w;
#pragma unroll
    for (int off = 32; off > 0; off >>= 1) ss += __shfl_xor(ss, off);
    const float inv = 1.0f / fmaxf(sqrtf(ss), 1e-12f);
    ushort4 h4, l4;
#define PCNV4(dst_h, dst_l, f) { float n_ = (f) * inv; u16 hb_ = bf_hi(n_); \
  dst_h = hb_; dst_l = bf_hi(n_ - bf_tof(hb_)); }
    PCNV4(h4.x, l4.x, a.x) PCNV4(h4.y, l4.y, a.y)
    PCNV4(h4.z, l4.z, a.z) PCNV4(h4.w, l4.w, a.w)
    *(ushort4*)(Ehi + (size_t)row * ND + lane * 4) = h4;
    *(ushort4*)(Elo + (size_t)row * ND + lane * 4) = l4;
    PCNV4(h4.x, l4.x, b.x) PCNV4(h4.y, l4.y, b.y)
    PCNV4(h4.z, l4.z, b.z) PCNV4(h4.w, l4.w, b.w)
    *(ushort4*)(Ehi + (size_t)row * ND + (lane + 64) * 4) = h4;
    *(ushort4*)(Elo + (size_t)row * ND + (lane + 64) * 4) = l4;
#undef PCNV4
  }
}

// online update with exact top-2 tracking (x-domain logit, fixed offset)
#define UPD2(r, vv, pp) { \
  float x_ = fmaf((vv), INV_T, -INV_T); \
  float e_ = __expf(x_); \
  sS[r] += e_; uS[r] = fmaf(x_, e_, uS[r]); \
  bool u1_ = x_ > m1[r]; \
  float lo_ = u1_ ? m1[r] : x_; \
  m2[r] = fmaxf(m2[r], lo_); \
  m1[r] = u1_ ? x_ : m1[r]; \
  ix[r] = u1_ ? (pp) : ix[r]; }

// ====== kernel 2: MFMA GEMM, [granule][row] LDS, counted-vmcnt pipeline =====
__global__ __launch_bounds__(256, 2) void kmain_v6(
    const float* __restrict__ BS,
    const u16* __restrict__ PhiG, const u16* __restrict__ PloG,
    const u16* __restrict__ EhiG, const u16* __restrict__ EloG,
    const float* __restrict__ CONF,
    float* __restrict__ tau_ws, float* __restrict__ gd, float* __restrict__ gate_out,
    int* __restrict__ cnt, int* __restrict__ flags, u64* __restrict__ pk) {
  // LDS u16 layouts: A [g(4)][row(64)][8] ; B [g(4)][proto(256)][8]
  __shared__ u16 Ahi[2][2048], Alo[2][2048];
  __shared__ u16 Bhi[2][8192], Blo[2][8192];

  const int t = threadIdx.x;
  const int lane = t & 63;
  const int w = t >> 6, wr = w >> 1, wc = w & 1;
  const int c = lane & 31, h = lane >> 5;
  const int swz = (blockIdx.x & 7) * 64 + (blockIdx.x >> 3);  // XCD swizzle (512=8*64)
  const int row0 = swz * 64;

  // A staging: thread t -> LDS slot t = (g=w)*64 + (row=lane); source strided
  const u16* EhiA = EhiG + (size_t)(row0 + lane) * ND + w * 8;
  const u16* EloA = EloG + (size_t)(row0 + lane) * ND + w * 8;

  // B staging: 4 instr/wave; slot index doubles as src offset (pre-transposed)
  int boff[4];
#pragma unroll
  for (int i = 0; i < 4; ++i) boff[i] = (w * 256 + i * 64 + lane) * 8;

  // fragment-read offsets (u16 units), lane-contiguous 16B -> conflict-free
  const int ao0 = ((h)*64 + wr * 32 + c) * 8;        // ks=0 granule h
  const int ao1 = ((2 + h) * 64 + wr * 32 + c) * 8;  // ks=1 granule 2+h
  const int bo0 = ((h)*256 + wc * 128 + c) * 8;
  const int bo1 = ((2 + h) * 256 + wc * 128 + c) * 8;

  f32x16 acc0, acc1, acc2, acc3;
#pragma unroll
  for (int i = 0; i < 16; ++i) { acc0[i] = 0.f; acc1[i] = 0.f; acc2[i] = 0.f; acc3[i] = 0.f; }
  float sS[16], uS[16], m1[16], m2[16];
  int ix[16];
#pragma unroll
  for (int r = 0; r < 16; ++r) {
    sS[r] = 0.f; uS[r] = 0.f; m1[r] = -3.0e38f; m2[r] = -3.0e38f; ix[r] = 0;
  }

#define SB6(tile_u16, nx) { \
  _Pragma("unroll") \
  for (int i = 0; i < 4; ++i) { \
    gload_lds16(PhiG + (tile_u16) + boff[i], &Bhi[nx][boff[i]]); \
    gload_lds16(PloG + (tile_u16) + boff[i], &Blo[nx][boff[i]]); \
  } }
#define SA6(col, nx) { \
  gload_lds16(EhiA + (col), &Ahi[nx][t * 8]); \
  gload_lds16(EloA + (col), &Alo[nx][t * 8]); }

  // prologue: stage step 0 -> buf0, step 1 -> buf1; wait step0 only
  SB6(0, 0);
  SA6(0, 0);
  SB6(8192, 1);
  SA6(32, 1);
  WAIT_VM10;
  SBAR;

#pragma unroll 2
  for (int step = 0; step < 128; ++step) {
    const int cur = step & 1;
    // ---- phase R: all 20 fragment reads from buf[cur] ----
    const bf16x8 eh0 = *(const bf16x8*)&Ahi[cur][ao0];
    const bf16x8 el0 = *(const bf16x8*)&Alo[cur][ao0];
    const bf16x8 eh1 = *(const bf16x8*)&Ahi[cur][ao1];
    const bf16x8 el1 = *(const bf16x8*)&Alo[cur][ao1];
    const bf16x8 bh00 = *(const bf16x8*)&Bhi[cur][bo0];
    const bf16x8 bh01 = *(const bf16x8*)&Bhi[cur][bo0 + 256];
    const bf16x8 bh02 = *(const bf16x8*)&Bhi[cur][bo0 + 512];
    const bf16x8 bh03 = *(const bf16x8*)&Bhi[cur][bo0 + 768];
    const bf16x8 bl00 = *(const bf16x8*)&Blo[cur][bo0];
    const bf16x8 bl01 = *(const bf16x8*)&Blo[cur][bo0 + 256];
    const bf16x8 bl02 = *(const bf16x8*)&Blo[cur][bo0 + 512];
    const bf16x8 bl03 = *(const bf16x8*)&Blo[cur][bo0 + 768];
    const bf16x8 bh10 = *(const bf16x8*)&Bhi[cur][bo1];
    const bf16x8 bh11 = *(const bf16x8*)&Bhi[cur][bo1 + 256];
    const bf16x8 bh12 = *(const bf16x8*)&Bhi[cur][bo1 + 512];
    const bf16x8 bh13 = *(const bf16x8*)&Bhi[cur][bo1 + 768];
    const bf16x8 bl10 = *(const bf16x8*)&Blo[cur][bo1];
    const bf16x8 bl11 = *(const bf16x8*)&Blo[cur][bo1 + 256];
    const bf16x8 bl12 = *(const bf16x8*)&Blo[cur][bo1 + 512];
    const bf16x8 bl13 = *(const bf16x8*)&Blo[cur][bo1 + 768];

    // ---- MFMA ks=0 ----
    acc0 = MF(eh0, bh00, acc0); acc1 = MF(eh0, bh01, acc1);
    acc2 = MF(eh0, bh02, acc2); acc3 = MF(eh0, bh03, acc3);
    acc0 = MF(eh0, bl00, acc0); acc1 = MF(eh0, bl01, acc1);
    acc2 = MF(eh0, bl02, acc2); acc3 = MF(eh0, bl03, acc3);
    acc0 = MF(el0, bh00, acc0); acc1 = MF(el0, bh01, acc1);
    acc2 = MF(el0, bh02, acc2); acc3 = MF(el0, bh03, acc3);

    // ---- barrier 1: all waves done READING buf[cur]; no vmcnt drain ----
    WAIT_LGKM0;
    SBAR;

    // ---- phase S: stage step+2 into buf[cur] ----
    const int ns = (step < 126) ? step + 2 : 127;  // tail dup, never read
    SB6(ns * 8192, cur);
    SA6((ns & 15) * 32, cur);

    // ---- MFMA ks=1 ----
    acc0 = MF(eh1, bh10, acc0); acc1 = MF(eh1, bh11, acc1);
    acc2 = MF(eh1, bh12, acc2); acc3 = MF(eh1, bh13, acc3);
    acc0 = MF(eh1, bl10, acc0); acc1 = MF(eh1, bl11, acc1);
    acc2 = MF(eh1, bl12, acc2); acc3 = MF(eh1, bl13, acc3);
    acc0 = MF(el1, bh10, acc0); acc1 = MF(el1, bh11, acc1);
    acc2 = MF(el1, bh12, acc2); acc3 = MF(el1, bh13, acc3);

    if ((step & 15) == 15) {  // kt-tile digest (overlaps in-flight stages)
      const int pidb = (step >> 4) * 256 + wc * 128 + c;
#pragma unroll
      for (int r = 0; r < 16; ++r) {
        UPD2(r, acc0[r], pidb)
        UPD2(r, acc1[r], pidb + 32)
        UPD2(r, acc2[r], pidb + 64)
        UPD2(r, acc3[r], pidb + 96)
        acc0[r] = 0.f; acc1[r] = 0.f; acc2[r] = 0.f; acc3[r] = 0.f;
      }
    }

    // ---- barrier 2: retire ONLY step t+1's 10 loads (counted vmcnt) ----
    WAIT_VM10;
    SBAR;
  }

  __syncthreads();  // full drain (tail dup-stages still write Ahi/Bhi)

  // ---- butterfly merge across the 32 proto-partition lanes ----
#pragma unroll
  for (int off = 1; off < 32; off <<= 1) {
#pragma unroll
    for (int r = 0; r < 16; ++r) {
      float m1o = __shfl_xor(m1[r], off);
      float m2o = __shfl_xor(m2[r], off);
      float so = __shfl_xor(sS[r], off);
      float uo = __shfl_xor(uS[r], off);
      int io = __shfl_xor(ix[r], off);
      sS[r] += so; uS[r] += uo;
      bool up = (m1o > m1[r]) || (m1o == m1[r] && io < ix[r]);
      float losr = (m1o > m1[r]) ? m1[r] : m1o;  // min(m1, m1o)
      m2[r] = fmaxf(fmaxf(m2[r], m2o), losr);
      m1[r] = fmaxf(m1[r], m1o);
      ix[r] = up ? io : ix[r];
    }
  }

  // ---- cross-wave (wc) merge via LDS (alias onto Ahi, compute done) ----
  float* mg = (float*)&Ahi[0][0];  // [wr][wc][32 rows][6]
  if (c == 0) {
#pragma unroll
    for (int r = 0; r < 16; ++r) {
      int rowl = (r & 3) + 8 * (r >> 2) + 4 * h;
      int base = ((wr * 2 + wc) * 32 + rowl) * 6;
      mg[base + 0] = m1[r];
      mg[base + 1] = sS[r];
      mg[base + 2] = uS[r];
      mg[base + 3] = __int_as_float(ix[r]);
      mg[base + 4] = m2[r];
    }
  }
  __syncthreads();

  if ((w & 1) == 0 && lane < 32) {
    const int rowl = lane;
    const int b0 = ((wr * 2 + 0) * 32 + rowl) * 6;
    const int b1 = ((wr * 2 + 1) * 32 + rowl) * 6;
    float m1a = mg[b0], s0 = mg[b0 + 1], u0 = mg[b0 + 2];
    int i0 = __float_as_int(mg[b0 + 3]);
    float m2a = mg[b0 + 4];
    float m1b = mg[b1], s1 = mg[b1 + 1], u1 = mg[b1 + 2];
    int i1 = __float_as_int(mg[b1 + 3]);
    float m2b = mg[b1 + 4];

    bool up = (m1b > m1a) || (m1b == m1a && i1 < i0);
    float m = fmaxf(m1a, m1b);
    float m2f = fmaxf(fmaxf(m2a, m2b), fminf(m1a, m1b));
    int idx = up ? i1 : i0;
    bool flg = (m - m2f) < DX;  // exact: final top-2 gap below margin
    float s = s0 + s1, u = u0 + u1;

    float ent = logf(s) - u / s;  // = lse - E[logit]
    float tau = 0.5f - 0.2f * (ent * (1.0f / (7.6246190071f + 1e-8f)));
    float simmax = fmaf(m, TEMPR, 1.0f);  // m is (sim-1)/T
    float dist = sqrtf(fmaxf(2.0f - 2.0f * simmax, 0.0f));
    int grow = row0 + wr * 32 + rowl;
    float g = CONF[idx] / (1.0f + __expf(-(BS[grow] - tau) * INV_T));
    gate_out[grow] = g;
    gd[grow] = g * dist;
    tau_ws[grow] = tau;
    if (flg) {
      pk[grow] = 0ull;  // init merge slot for krescore4
      int p = atomicAdd(cnt, 1);
      flags[p] = grow;
    }
  }
}

// --- kernel 3: fp32 rescore, chunked (16 chunks/row fan out over blocks) ----
// Chunk = 128 protos. Merge via atomicMax on packed (ordered_sim<<32 | NK-idx):
// exact fp32 compare, smaller idx wins ties, order-independent.
__global__ __launch_bounds__(256) void krescore4(
    const float* __restrict__ E, const float* __restrict__ P,
    const float* __restrict__ invp, const int* __restrict__ cnt,
    const int* __restrict__ flags, u64* __restrict__ pk) {
  const int n = *cnt;
  const int total = n * 16;
  const int t = threadIdx.x;
  const int k = t & 15;   // lane in 16-lane group
  const int G = t >> 4;   // group 0..15

  for (int ch = blockIdx.x; ch < total; ch += gridDim.x) {
    const int j = ch >> 4, q = ch & 15;
    const int row = flags[j];
    float4 e[8];
    float ss = 0.f;
    const float4* er = (const float4*)(E + (size_t)row * ND);
#pragma unroll
    for (int i = 0; i < 8; ++i) {
      e[i] = er[k + 16 * i];
      ss += e[i].x * e[i].x + e[i].y * e[i].y + e[i].z * e[i].z + e[i].w * e[i].w;
    }
#pragma unroll
    for (int o = 1; o < 16; o <<= 1) ss += __shfl_xor(ss, o);
    const float inv = 1.0f / fmaxf(sqrtf(ss), 1e-12f);
#pragma unroll
    for (int i = 0; i < 8; ++i) {
      e[i].x *= inv; e[i].y *= inv; e[i].z *= inv; e[i].w *= inv;
    }

    float best = -3.0e38f;
    int bidx = NK;
#pragma unroll 2
    for (int m = 0; m < 8; ++m) {  // ascending p within group: first-max kept
      const int p = q * 128 + G + 16 * m;
      const float4* pr = (const float4*)(P + (size_t)p * ND);
      float dot = 0.f;
#pragma unroll
      for (int i = 0; i < 8; ++i) {
        float4 a = pr[k + 16 * i];
        dot = fmaf(a.x, e[i].x, dot); dot = fmaf(a.y, e[i].y, dot);
        dot = fmaf(a.z, e[i].z, dot); dot = fmaf(a.w, e[i].w, dot);
      }
#pragma unroll
      for (int o = 1; o < 16; o <<= 1) dot += __shfl_xor(dot, o);
      float sim = dot * invp[p];
      if (sim > best) { best = sim; bidx = p; }
    }
    if (k == 0) {
      unsigned u = __float_as_uint(best);
      unsigned ord = (u & 0x80000000u) ? ~u : (u | 0x80000000u);
      u64 v = ((u64)ord << 32) | (unsigned)(NK - bidx);
      atomicMax(pk + row, v);
    }
  }
}

// ------- kernel 4: flagged-row fixup (unpack pk) + deterministic mean -------
__global__ __launch_bounds__(1024) void kreduce2(
    float* __restrict__ gd, const float* __restrict__ BS,
    const float* __restrict__ CONF, const float* __restrict__ tau_ws,
    const int* __restrict__ cnt, const int* __restrict__ flags,
    const u64* __restrict__ pk, float* __restrict__ out0,
    float* __restrict__ gate_out) {
  __shared__ float red[1024];
  const int t = threadIdx.x;

  // ---- phase 1: fixup flagged rows from packed rescore results ----
  const int n = *cnt;
  for (int j = t; j < n; j += 1024) {
    const int row = flags[j];
    const u64 v = pk[row];
    const unsigned hi = (unsigned)(v >> 32);
    const int idx = NK - (int)(v & 0xFFFFFFFFu);
    const float sim = (hi & 0x80000000u) ? __uint_as_float(hi & 0x7FFFFFFFu)
                                         : __uint_as_float(~hi);
    const float tau = tau_ws[row];
    const float dist = sqrtf(fmaxf(2.0f - 2.0f * sim, 0.0f));
    const float g = CONF[idx] / (1.0f + __expf(-(BS[row] - tau) * INV_T));
    gate_out[row] = g;
    gd[row] = g * dist;
  }
  __syncthreads();  // block-wide visibility of gd fixups

  // ---- phase 2: deterministic mean ----
  float s = 0.f;
  const float4* g4 = (const float4*)gd;
  for (int i = t; i < 8192; i += 1024) {
    float4 v = g4[i];
    s += (v.x + v.y) + (v.z + v.w);
  }
  red[t] = s;
  __syncthreads();
  for (int off = 512; off > 0; off >>= 1) {
    if (t < off) red[t] += red[t + off];
    __syncthreads();
  }
  if (t == 0) out0[0] = red[0] * (1.0f / 32768.0f);
}

extern "C" void kernel_launch(void* const* d_in, const int* in_sizes, int n_in,
                              void* d_out, int out_size, void* d_ws, size_t ws_size,
                              hipStream_t stream) {
  const float* E = (const float*)d_in[0];
  const float* BS = (const float*)d_in[1];
  const float* P = (const float*)d_in[2];
  const float* CONF = (const float*)d_in[3];
  float* out = (float*)d_out;  // [0]=L_proto, [1..32768]=gate

  char* wsb = (char*)d_ws;
  u16* Phi = (u16*)wsb;                                   // 2 MB @ 0 (transposed)
  u16* Plo = (u16*)(wsb + ((size_t)2 << 20));             // 2 MB @ 2M (transposed)
  u16* Ehi = (u16*)(wsb + ((size_t)4 << 20));             // 32 MB @ 4M (row-major)
  u16* Elo = (u16*)(wsb + ((size_t)36 << 20));            // 32 MB @ 36M
  char* tail = wsb + ((size_t)68 << 20);
  float* tau_ws = (float*)tail;                           // 128 KB
  float* gd = (float*)(tail + 131072);                    // 128 KB
  int* flags = (int*)(tail + 2 * 131072);                 // 128 KB
  int* cnt = (int*)(tail + 3 * 131072);                   // 4 KB pad
  float* invp = (float*)(tail + 3 * 131072 + 4096);       // 8 KB
  u64* pk = (u64*)(tail + 3 * 131072 + 4096 + 8192);      // 256 KB

  kprep_all<<<8704, 256, 0, stream>>>(P, E, Phi, Plo, invp, Ehi, Elo, cnt);
  kmain_v6<<<512, 256, 0, stream>>>(BS, Phi, Plo, Ehi, Elo, CONF, tau_ws, gd,
                                    out + 1, cnt, flags, pk);
  krescore4<<<2048, 256, 0, stream>>>(E, P, invp, cnt, flags, pk);
  kreduce2<<<1, 1024, 0, stream>>>(gd, BS, CONF, tau_ws, cnt, flags, pk,
                                   out, out + 1);
}